// Round 2
// baseline (250.417 us; speedup 1.0000x reference)
//
#include <hip/hip_runtime.h>

#define N_PIX   32768
#define DIM     64
#define K_CODES 1024
#define NCHUNK  8
#define CHUNK   (K_CODES / NCHUNK)   // 128

// ws layout:
//   [0, 4096)                 : c2[1024] (float)
//   [4096, 4096 + 2 MiB)      : partials float2[NCHUNK][N_PIX]  (dist, idx-as-float-bits)

__global__ __launch_bounds__(256) void c2_kernel(const float* __restrict__ cb,
                                                 float* __restrict__ c2) {
    int k = blockIdx.x * 256 + threadIdx.x;
    if (k >= K_CODES) return;
    const float* row = cb + k * DIM;
    float a0 = 0.f, a1 = 0.f, a2 = 0.f, a3 = 0.f;
#pragma unroll
    for (int d = 0; d < DIM; d += 4) {
        a0 = fmaf(row[d + 0], row[d + 0], a0);
        a1 = fmaf(row[d + 1], row[d + 1], a1);
        a2 = fmaf(row[d + 2], row[d + 2], a2);
        a3 = fmaf(row[d + 3], row[d + 3], a3);
    }
    c2[k] = (a0 + a1) + (a2 + a3);
}

// One thread = one pixel; one block = 256 pixels x 128 codes.
// grid.x = (N_PIX/256) * NCHUNK = 128 * 8 = 1024 blocks.
__global__ __launch_bounds__(256) void argmin_partial(const float* __restrict__ x,
                                                      const float* __restrict__ cb,
                                                      const float* __restrict__ c2,
                                                      float2* __restrict__ part) {
    int blk    = blockIdx.x;
    int pixblk = blk >> 3;       // 0..127
    int chunk  = blk & 7;        // 0..7
    int p  = pixblk * 256 + threadIdx.x;   // pixel id in [0, 32768)
    int bb = p >> 10;            // batch
    int hw = p & 1023;           // h*32+w

    // x is [B, D, H, W]: element (bb, d, hw) at bb*DIM*1024 + d*1024 + hw.
    const float* xbase = x + (size_t)bb * (DIM * 1024) + hw;
    float xv[DIM];
#pragma unroll
    for (int d = 0; d < DIM; ++d) xv[d] = xbase[(size_t)d * 1024];

    // x2 = sum of squares. Rounding details of this reduction shift all d2[k]
    // by the same multiple of the local ulp -> argmin-invariant.
    float s0 = 0.f, s1 = 0.f, s2 = 0.f, s3 = 0.f;
#pragma unroll
    for (int d = 0; d < DIM; d += 4) {
        s0 = fmaf(xv[d + 0], xv[d + 0], s0);
        s1 = fmaf(xv[d + 1], xv[d + 1], s1);
        s2 = fmaf(xv[d + 2], xv[d + 2], s2);
        s3 = fmaf(xv[d + 3], xv[d + 3], s3);
    }
    float x2 = (s0 + s1) + (s2 + s3);

    float best = 1e30f;
    int   bidx = 0;
    int   k0   = chunk * CHUNK;
#pragma unroll 2
    for (int k = k0; k < k0 + CHUNK; ++k) {
        const float* crow = cb + k * DIM;   // wave-uniform -> s_load + v_fma v,s,v
        float a0 = 0.f, a1 = 0.f, a2 = 0.f, a3 = 0.f;
#pragma unroll
        for (int d = 0; d < DIM; d += 4) {
            a0 = fmaf(xv[d + 0], crow[d + 0], a0);
            a1 = fmaf(xv[d + 1], crow[d + 1], a1);
            a2 = fmaf(xv[d + 2], crow[d + 2], a2);
            a3 = fmaf(xv[d + 3], crow[d + 3], a3);
        }
        float dot = (a0 + a1) + (a2 + a3);
        // Replicate reference rounding: d2 = (x2 - 2*dot) + c2.
        // The rounding at magnitude ~64 (ulp 7.6e-6) quantizes distances and
        // stabilizes tie-breaking to match the fp32 reference exactly.
        float t    = x2 - 2.0f * dot;   // fma-contraction safe: 2*dot is exact
        float dist = t + c2[k];
        if (dist < best) { best = dist; bidx = k; }   // strict <: first-min ties
    }
    float2 r;
    r.x = best;
    r.y = __int_as_float(bidx);
    part[(size_t)chunk * N_PIX + p] = r;   // coalesced
}

// One block = 32 rows. Writes one-hot rows (fused zero-fill) + quantized.
// grid.x = N_PIX / 32 = 1024 blocks.
__global__ __launch_bounds__(256) void finalize(const float* __restrict__ cb,
                                                const float2* __restrict__ part,
                                                float* __restrict__ enc,
                                                float* __restrict__ quant) {
    __shared__ int sidx[32];
    int block = blockIdx.x;
    int t     = threadIdx.x;

    if (t < 32) {
        int   n    = block * 32 + t;
        float best = 1e30f;
        int   bidx = 0;
#pragma unroll
        for (int c = 0; c < NCHUNK; ++c) {
            float2 r = part[(size_t)c * N_PIX + n];
            if (r.x < best) { best = r.x; bidx = __float_as_int(r.y); }
        }
        sidx[t] = bidx;
    }
    __syncthreads();

    // encodings: 32 rows x 1024 floats, one float4 per thread per row (coalesced)
    int j0 = t * 4;
#pragma unroll 4
    for (int r = 0; r < 32; ++r) {
        int    n  = block * 32 + r;
        int    ir = sidx[r];
        float4 v;
        v.x = (ir == j0 + 0) ? 1.0f : 0.0f;
        v.y = (ir == j0 + 1) ? 1.0f : 0.0f;
        v.z = (ir == j0 + 2) ? 1.0f : 0.0f;
        v.w = (ir == j0 + 3) ? 1.0f : 0.0f;
        *reinterpret_cast<float4*>(enc + (size_t)n * K_CODES + j0) = v;
    }

    // quantized [B, D, H, W]: thread t -> row r = t&31, dims [ (t>>5)*8 , +8 )
    int r  = t & 31;
    int d0 = (t >> 5) * 8;
    int n  = block * 32 + r;
    int bb = n >> 10;
    int hw = n & 1023;
    int ir = sidx[r];
#pragma unroll
    for (int dd = 0; dd < 8; ++dd) {
        int d = d0 + dd;
        quant[(size_t)bb * (DIM * 1024) + (size_t)d * 1024 + hw] = cb[ir * DIM + d];
    }
}

extern "C" void kernel_launch(void* const* d_in, const int* in_sizes, int n_in,
                              void* d_out, int out_size, void* d_ws, size_t ws_size,
                              hipStream_t stream) {
    const float* x  = (const float*)d_in[0];
    const float* cb = (const float*)d_in[1];

    float*  c2   = (float*)d_ws;
    float2* part = (float2*)((char*)d_ws + 4096);

    float* enc   = (float*)d_out;                          // [32768, 1024]
    float* quant = (float*)d_out + (size_t)N_PIX * K_CODES; // [32, 64, 32, 32]

    c2_kernel<<<K_CODES / 256, 256, 0, stream>>>(cb, c2);
    argmin_partial<<<(N_PIX / 256) * NCHUNK, 256, 0, stream>>>(x, cb, c2, part);
    finalize<<<N_PIX / 32, 256, 0, stream>>>(cb, part, enc, quant);
}

// Round 3
// 230.497 us; speedup vs baseline: 1.0864x; 1.0864x over previous
//
#include <hip/hip_runtime.h>

#define N_PIX   32768
#define DIM     64
#define K_CODES 1024
#define NCHUNK  8
#define CHUNK   (K_CODES / NCHUNK)   // 128

// ws layout:
//   [0, 4096)                       : c2[1024] (float)
//   [4096, 4096 + 2 MiB)            : partials float2[NCHUNK][N_PIX]
//   [4096 + 2 MiB, + 128 KiB)       : idx[N_PIX] (int)

__global__ __launch_bounds__(256) void c2_kernel(const float* __restrict__ cb,
                                                 float* __restrict__ c2) {
    int k = blockIdx.x * 256 + threadIdx.x;
    if (k >= K_CODES) return;
    const float* row = cb + k * DIM;
    float a0 = 0.f, a1 = 0.f, a2 = 0.f, a3 = 0.f;
#pragma unroll
    for (int d = 0; d < DIM; d += 4) {
        a0 = fmaf(row[d + 0], row[d + 0], a0);
        a1 = fmaf(row[d + 1], row[d + 1], a1);
        a2 = fmaf(row[d + 2], row[d + 2], a2);
        a3 = fmaf(row[d + 3], row[d + 3], a3);
    }
    c2[k] = (a0 + a1) + (a2 + a3);
}

// P=2 pixels per thread. One block = 512 pixels x 128 codes.
// grid = (N_PIX/512) * NCHUNK = 64 * 8 = 512 blocks (2 blocks/CU exactly).
// __launch_bounds__(256, 2): VGPR budget 256 so xv0/xv1 (128 floats) stay in
// arch VGPRs (round-2 showed VGPR_Count=48 -> compiler evicted xv -> stalls).
__global__ __launch_bounds__(256, 2) void argmin_p2(const float* __restrict__ x,
                                                    const float* __restrict__ cb,
                                                    const float* __restrict__ c2,
                                                    float2* __restrict__ part) {
    int blk    = blockIdx.x;
    int pixblk = blk >> 3;       // 0..63
    int chunk  = blk & 7;        // 0..7
    int p0 = pixblk * 512 + threadIdx.x;   // second pixel is p0 + 256
    int bb = p0 >> 10;           // batch (same for p0 and p0+256: 512 | 1024)
    int hw = p0 & 1023;

    const float* xb0 = x + (size_t)bb * (DIM * 1024) + hw;
    const float* xb1 = xb0 + 256;
    float xv0[DIM], xv1[DIM];
#pragma unroll
    for (int d = 0; d < DIM; ++d) {
        xv0[d] = xb0[(size_t)d << 10];
        xv1[d] = xb1[(size_t)d << 10];
    }

    // x2 per pixel — same tree as the passing round-2 kernel (argmin-invariant
    // to this reduction's rounding, but keep it identical anyway).
    float s0 = 0.f, s1 = 0.f, s2 = 0.f, s3 = 0.f;
    float t0 = 0.f, t1 = 0.f, t2 = 0.f, t3 = 0.f;
#pragma unroll
    for (int d = 0; d < DIM; d += 4) {
        s0 = fmaf(xv0[d + 0], xv0[d + 0], s0);
        s1 = fmaf(xv0[d + 1], xv0[d + 1], s1);
        s2 = fmaf(xv0[d + 2], xv0[d + 2], s2);
        s3 = fmaf(xv0[d + 3], xv0[d + 3], s3);
        t0 = fmaf(xv1[d + 0], xv1[d + 0], t0);
        t1 = fmaf(xv1[d + 1], xv1[d + 1], t1);
        t2 = fmaf(xv1[d + 2], xv1[d + 2], t2);
        t3 = fmaf(xv1[d + 3], xv1[d + 3], t3);
    }
    float x20 = (s0 + s1) + (s2 + s3);
    float x21 = (t0 + t1) + (t2 + t3);

    float best0 = 1e30f, best1 = 1e30f;
    int   bi0 = 0, bi1 = 0;
    int   k0 = chunk * CHUNK;
#pragma unroll 2
    for (int k = k0; k < k0 + CHUNK; ++k) {
        const float* crow = cb + k * DIM;   // wave-uniform -> scalar loads
        float c2k = c2[k];
        float a0 = 0.f, a1 = 0.f, a2 = 0.f, a3 = 0.f;
        float b0 = 0.f, b1 = 0.f, b2 = 0.f, b3 = 0.f;
#pragma unroll
        for (int d = 0; d < DIM; d += 4) {
            float w0 = crow[d + 0], w1 = crow[d + 1];
            float w2 = crow[d + 2], w3 = crow[d + 3];
            a0 = fmaf(xv0[d + 0], w0, a0);
            a1 = fmaf(xv0[d + 1], w1, a1);
            a2 = fmaf(xv0[d + 2], w2, a2);
            a3 = fmaf(xv0[d + 3], w3, a3);
            b0 = fmaf(xv1[d + 0], w0, b0);
            b1 = fmaf(xv1[d + 1], w1, b1);
            b2 = fmaf(xv1[d + 2], w2, b2);
            b3 = fmaf(xv1[d + 3], w3, b3);
        }
        float dot0 = (a0 + a1) + (a2 + a3);
        float dot1 = (b0 + b1) + (b2 + b3);
        // Reference rounding structure: d2 = (x2 - 2*dot) + c2 (ulp-64 grid
        // quantization stabilizes tie-breaking — verified exact in round 2).
        float u0 = x20 - 2.0f * dot0;
        float u1 = x21 - 2.0f * dot1;
        float d0 = u0 + c2k;
        float d1 = u1 + c2k;
        if (d0 < best0) { best0 = d0; bi0 = k; }   // strict <: first-min ties
        if (d1 < best1) { best1 = d1; bi1 = k; }
    }
    float2 r0; r0.x = best0; r0.y = __int_as_float(bi0);
    float2 r1; r1.x = best1; r1.y = __int_as_float(bi1);
    part[(size_t)chunk * N_PIX + p0]       = r0;   // coalesced
    part[(size_t)chunk * N_PIX + p0 + 256] = r1;
}

// Reduce the 8 partials per pixel (ascending chunk, strict < -> first-min),
// store idx, and write quantized [B, D, H, W].
// grid = N_PIX/128 = 256 blocks x 128 threads.
__global__ __launch_bounds__(128) void reduce_quant(const float* __restrict__ cb,
                                                    const float2* __restrict__ part,
                                                    int* __restrict__ idx,
                                                    float* __restrict__ quant) {
    int n = blockIdx.x * 128 + threadIdx.x;
    float best = 1e30f;
    int   bi = 0;
#pragma unroll
    for (int c = 0; c < NCHUNK; ++c) {
        float2 r = part[(size_t)c * N_PIX + n];
        if (r.x < best) { best = r.x; bi = __float_as_int(r.y); }
    }
    idx[n] = bi;

    int bb = n >> 10;
    int hw = n & 1023;
    const float4* crow = reinterpret_cast<const float4*>(cb + (size_t)bi * DIM);
    float* qb = quant + (size_t)bb * (DIM * 1024) + hw;
#pragma unroll
    for (int dq = 0; dq < 16; ++dq) {
        float4 cv = crow[dq];            // L2-resident gather
        qb[(size_t)(dq * 4 + 0) << 10] = cv.x;   // lanes: consecutive hw -> coalesced
        qb[(size_t)(dq * 4 + 1) << 10] = cv.y;
        qb[(size_t)(dq * 4 + 2) << 10] = cv.z;
        qb[(size_t)(dq * 4 + 3) << 10] = cv.w;
    }
}

// Pure streaming one-hot writer: flat float4 index e covers enc[n][j0..j0+3]
// with n = e>>8, j0 = (e&255)*4. grid-stride, 2048 blocks.
__global__ __launch_bounds__(256) void enc_write(const int* __restrict__ idx,
                                                 float* __restrict__ enc) {
    const int TOT = (N_PIX / 4) * K_CODES;   // 8388608 float4s
    int tid = blockIdx.x * 256 + threadIdx.x;
    float4* enc4 = reinterpret_cast<float4*>(enc);
    for (int e = tid; e < TOT; e += 2048 * 256) {
        int n  = e >> 8;
        int j0 = (e & 255) << 2;
        int ir = idx[n];                 // same address across the row's waves -> broadcast
        float4 v;
        v.x = (ir == j0 + 0) ? 1.0f : 0.0f;
        v.y = (ir == j0 + 1) ? 1.0f : 0.0f;
        v.z = (ir == j0 + 2) ? 1.0f : 0.0f;
        v.w = (ir == j0 + 3) ? 1.0f : 0.0f;
        enc4[e] = v;
    }
}

extern "C" void kernel_launch(void* const* d_in, const int* in_sizes, int n_in,
                              void* d_out, int out_size, void* d_ws, size_t ws_size,
                              hipStream_t stream) {
    const float* x  = (const float*)d_in[0];
    const float* cb = (const float*)d_in[1];

    float*  c2   = (float*)d_ws;
    float2* part = (float2*)((char*)d_ws + 4096);
    int*    idx  = (int*)((char*)d_ws + 4096 + (size_t)NCHUNK * N_PIX * 8);

    float* enc   = (float*)d_out;                           // [32768, 1024]
    float* quant = (float*)d_out + (size_t)N_PIX * K_CODES; // [32, 64, 32, 32]

    c2_kernel<<<K_CODES / 256, 256, 0, stream>>>(cb, c2);
    argmin_p2<<<(N_PIX / 512) * NCHUNK, 256, 0, stream>>>(x, cb, c2, part);
    reduce_quant<<<N_PIX / 128, 128, 0, stream>>>(cb, part, idx, quant);
    enc_write<<<2048, 256, 0, stream>>>(idx, enc);
}